// Round 2
// baseline (1012.611 us; speedup 1.0000x reference)
//
#include <hip/hip_runtime.h>

#define EPS 1e-12f
#define CAP 32   // ELL slots/vertex. deg ~ Poisson(6); P(deg>32) ~ 1e-15/vertex -> no spill path needed
#define NB 4     // batches per gather thread

// ---------------------------------------------------------------------------
// Pipeline (3 kernels): zero cursor -> fill ELL (atomicAdd slot alloc)
//                       -> gather4 (slot-major ELL, 4 batches/thread)
//
// ELL entry at slot s of vertex v stores the other two indices (a,b) of one
// incident face corner, in cyclic order; contribution = (A-v) x (B-v), which
// equals the reference's cross(v2-v1, v0-v1) for every corner (cyclic
// identity). Slot-major layout ell[s*V + v] makes the adjacency reads fully
// coalesced across lanes; adjacency is identical for all batches, so each
// thread amortizes it over NB=4 batches (8 independent random vertex loads
// per slot -> 8-way MLP). Batch-groups pinned to XCDs (8 groups, blockIdx%8
// round-robin); only output stores are non-temporal.
// ---------------------------------------------------------------------------

__global__ void zero_ints(int* __restrict__ p, int n) {
    int i = blockIdx.x * blockDim.x + threadIdx.x;
    if (i < n) p[i] = 0;
}

__global__ void fill_ell(const int* __restrict__ faces, int* __restrict__ cursor,
                         int2* __restrict__ ell, int F, int V) {
    int f = blockIdx.x * blockDim.x + threadIdx.x;
    if (f >= F) return;
    int i0 = faces[3 * f + 0];
    int i1 = faces[3 * f + 1];
    int i2 = faces[3 * f + 2];
    int vs[3] = {i0, i1, i2};
    int as[3] = {i1, i2, i0};
    int bs[3] = {i2, i0, i1};
#pragma unroll
    for (int c = 0; c < 3; c++) {
        int v = vs[c];
        int slot = atomicAdd(&cursor[v], 1);
        if (slot < CAP) ell[slot * V + v] = make_int2(as[c], bs[c]);
    }
}

__global__ __launch_bounds__(256) void gather4(const float* __restrict__ verts,
                                               const int* __restrict__ deg,
                                               const int2* __restrict__ ell,
                                               float* __restrict__ out,
                                               int V, int ngrp) {
    int blk = blockIdx.x;
    int grp = blk % ngrp;        // ngrp==8 -> grp == XCD id (round-robin dispatch)
    int vblk = blk / ngrp;
    int v = vblk * 256 + threadIdx.x;
    if (v >= V) return;

    const float* vb[NB];
    float px[NB], py[NB], pz[NB];
    float ax[NB], ay[NB], az[NB];
#pragma unroll
    for (int g = 0; g < NB; g++) {
        vb[g] = verts + (size_t)(grp * NB + g) * V * 3;
        px[g] = vb[g][3 * v + 0];
        py[g] = vb[g][3 * v + 1];
        pz[g] = vb[g][3 * v + 2];
        ax[g] = 0.f; ay[g] = 0.f; az[g] = 0.f;
    }

    int d = min(deg[v], CAP);
    for (int s = 0; s < d; s++) {
        int2 p = ell[s * V + v];   // coalesced: lane stride = 8 B
        int ia = 3 * p.x;
        int ib = 3 * p.y;
#pragma unroll
        for (int g = 0; g < NB; g++) {
            float aX = vb[g][ia + 0] - px[g];
            float aY = vb[g][ia + 1] - py[g];
            float aZ = vb[g][ia + 2] - pz[g];
            float bX = vb[g][ib + 0] - px[g];
            float bY = vb[g][ib + 1] - py[g];
            float bZ = vb[g][ib + 2] - pz[g];
            ax[g] += aY * bZ - aZ * bY;
            ay[g] += aZ * bX - aX * bZ;
            az[g] += aX * bY - aY * bX;
        }
    }

#pragma unroll
    for (int g = 0; g < NB; g++) {
        float sc = rsqrtf(fmaxf(ax[g] * ax[g] + ay[g] * ay[g] + az[g] * az[g], EPS));
        size_t o = ((size_t)(grp * NB + g) * V + v) * 3;
        __builtin_nontemporal_store(ax[g] * sc, out + o + 0);
        __builtin_nontemporal_store(ay[g] * sc, out + o + 1);
        __builtin_nontemporal_store(az[g] * sc, out + o + 2);
    }
}

extern "C" void kernel_launch(void* const* d_in, const int* in_sizes, int n_in,
                              void* d_out, int out_size, void* d_ws, size_t ws_size,
                              hipStream_t stream) {
    const float* verts = (const float*)d_in[0];
    const int* faces = (const int*)d_in[1];
    float* out = (float*)d_out;

    const int V = 200000;
    const int F = in_sizes[1] / 3;           // 400000
    const int B = in_sizes[0] / (3 * V);     // 32

    // workspace: cursor[V] | ell[CAP*V] (int2)  -> ~52 MB
    int* cursor = (int*)d_ws;
    int2* ell = (int2*)(cursor + V);

    zero_ints<<<(V + 255) / 256, 256, 0, stream>>>(cursor, V);
    fill_ell<<<(F + 255) / 256, 256, 0, stream>>>(faces, cursor, ell, F, V);

    int vpb = (V + 255) / 256;               // 782 vertex-blocks per group
    int ngrp = B / NB;                       // 8 batch-groups -> 8 XCDs
    gather4<<<ngrp * vpb, 256, 0, stream>>>(verts, cursor, ell, out, V, ngrp);
}

// Round 3
// 765.367 us; speedup vs baseline: 1.3230x; 1.3230x over previous
//
#include <hip/hip_runtime.h>

#define EPS 1e-12f
#define CAP 32   // ELL slots/vertex. deg ~ Poisson(6); P(deg>=32) ~ 1e-13/vertex -> no spill path

// ---------------------------------------------------------------------------
// Pipeline: zero cursor -> fill ELL (slot-major) -> repack verts to float4
//           -> gather (NB=1, batch pinned to XCD, ELL/deg streamed NT)
//
// ELL entry at slot s of vertex v stores the other two indices (a,b) of one
// incident face corner, in cyclic order; contribution = (A-v) x (B-v) equals
// the reference's cross(v2-v1, v0-v1) for every corner (cyclic identity).
//
// Regime learned from rounds 0-2: scattered L2-miss (fabric) traffic
// saturates at ~3.7 TB/s and duration ~ FETCH_SIZE, so the design goal is
// L2 residency of the random-read set:
//   - one batch per XCD at a time  -> 3.2 MB verts4 < 4 MiB L2
//   - ELL/deg streams NT (coalesced -> full line use, no L2 pollution)
//   - float4-padded verts -> one aligned 16B load per neighbor
// ---------------------------------------------------------------------------

__global__ void zero_ints(int* __restrict__ p, int n) {
    int i = blockIdx.x * blockDim.x + threadIdx.x;
    if (i < n) p[i] = 0;
}

__global__ void fill_ell(const int* __restrict__ faces, int* __restrict__ cursor,
                         int2* __restrict__ ell, int F, int V) {
    int f = blockIdx.x * blockDim.x + threadIdx.x;
    if (f >= F) return;
    int i0 = faces[3 * f + 0];
    int i1 = faces[3 * f + 1];
    int i2 = faces[3 * f + 2];
    int vs[3] = {i0, i1, i2};
    int as[3] = {i1, i2, i0};
    int bs[3] = {i2, i0, i1};
#pragma unroll
    for (int c = 0; c < 3; c++) {
        int v = vs[c];
        int slot = atomicAdd(&cursor[v], 1);
        if (slot < CAP) ell[slot * V + v] = make_int2(as[c], bs[c]);
    }
}

// 4 vertices (12 floats = 3 float4) -> 4 padded float4 per thread, fully coalesced
__global__ void repack4(const float4* __restrict__ in4, float4* __restrict__ out4,
                        size_t nvtx) {
    size_t t = (size_t)blockIdx.x * blockDim.x + threadIdx.x;
    if (t * 4 >= nvtx) return;
    float4 a = in4[3 * t + 0];
    float4 b = in4[3 * t + 1];
    float4 c = in4[3 * t + 2];
    out4[4 * t + 0] = make_float4(a.x, a.y, a.z, 0.f);
    out4[4 * t + 1] = make_float4(a.w, b.x, b.y, 0.f);
    out4[4 * t + 2] = make_float4(b.z, b.w, c.x, 0.f);
    out4[4 * t + 3] = make_float4(c.y, c.z, c.w, 0.f);
}

template <bool USE4>
__global__ __launch_bounds__(256) void gather1(const float* __restrict__ verts,
                                               const float4* __restrict__ verts4,
                                               const int* __restrict__ deg,
                                               const int2* __restrict__ ell,
                                               float* __restrict__ out,
                                               int V, int vpb, int B) {
    int i = blockIdx.x;
    int xcd = i & 7;                 // round-robin dispatch -> XCD id
    int j = i >> 3;
    int lb = j / vpb;                // local batch index on this XCD
    int vblk = j - lb * vpb;
    int batch = lb * 8 + xcd;
    if (batch >= B) return;
    int v = vblk * 256 + threadIdx.x;
    if (v >= V) return;

    const float* vb = verts + (size_t)batch * V * 3;
    const float4* vb4 = verts4 + (size_t)batch * V;

    float vx, vy, vz;
    if (USE4) {
        float4 c = vb4[v];
        vx = c.x; vy = c.y; vz = c.z;
    } else {
        vx = vb[3 * v + 0]; vy = vb[3 * v + 1]; vz = vb[3 * v + 2];
    }

    int d = min(__builtin_nontemporal_load(deg + v), CAP);
    float ax = 0.f, ay = 0.f, az = 0.f;

    const unsigned long long* ep = (const unsigned long long*)ell;
    unsigned long long cur = 0;
    if (d > 0) cur = __builtin_nontemporal_load(ep + v);  // slot 0
    for (int s = 0; s < d; s++) {
        unsigned long long nxt = 0;
        if (s + 1 < d)
            nxt = __builtin_nontemporal_load(ep + (size_t)(s + 1) * V + v);
        int pa = (int)(unsigned int)(cur & 0xffffffffull);
        int pb = (int)(unsigned int)(cur >> 32);
        float Ax, Ay, Az, Bx, By, Bz;
        if (USE4) {
            float4 A = vb4[pa];
            float4 Bq = vb4[pb];
            Ax = A.x; Ay = A.y; Az = A.z;
            Bx = Bq.x; By = Bq.y; Bz = Bq.z;
        } else {
            Ax = vb[3 * pa + 0]; Ay = vb[3 * pa + 1]; Az = vb[3 * pa + 2];
            Bx = vb[3 * pb + 0]; By = vb[3 * pb + 1]; Bz = vb[3 * pb + 2];
        }
        float aX = Ax - vx, aY = Ay - vy, aZ = Az - vz;
        float bX = Bx - vx, bY = By - vy, bZ = Bz - vz;
        ax += aY * bZ - aZ * bY;
        ay += aZ * bX - aX * bZ;
        az += aX * bY - aY * bX;
        cur = nxt;
    }

    float sc = rsqrtf(fmaxf(ax * ax + ay * ay + az * az, EPS));
    size_t o = ((size_t)batch * V + v) * 3;
    __builtin_nontemporal_store(ax * sc, out + o + 0);
    __builtin_nontemporal_store(ay * sc, out + o + 1);
    __builtin_nontemporal_store(az * sc, out + o + 2);
}

extern "C" void kernel_launch(void* const* d_in, const int* in_sizes, int n_in,
                              void* d_out, int out_size, void* d_ws, size_t ws_size,
                              hipStream_t stream) {
    const float* verts = (const float*)d_in[0];
    const int* faces = (const int*)d_in[1];
    float* out = (float*)d_out;

    const int V = 200000;
    const int F = in_sizes[1] / 3;           // 400000
    const int B = in_sizes[0] / (3 * V);     // 32

    size_t verts4B = (size_t)B * V * sizeof(float4);   // 102.4 MB
    size_t cursorB = (size_t)V * sizeof(int);          // 0.8 MB
    size_t ellB = (size_t)CAP * V * sizeof(int2);      // 51.2 MB
    bool use4 = ws_size >= verts4B + cursorB + ellB + 256;

    char* w = (char*)d_ws;
    float4* verts4 = nullptr;
    if (use4) { verts4 = (float4*)w; w += verts4B; }
    int* cursor = (int*)w; w += cursorB;               // 0.8 MB, 8B-divisible
    int2* ell = (int2*)w;

    zero_ints<<<(V + 255) / 256, 256, 0, stream>>>(cursor, V);
    fill_ell<<<(F + 255) / 256, 256, 0, stream>>>(faces, cursor, ell, F, V);
    if (use4) {
        size_t nvtx = (size_t)B * V;                   // 6.4M, divisible by 4
        int nthr = (int)(nvtx / 4);                    // 1.6M
        repack4<<<(nthr + 255) / 256, 256, 0, stream>>>((const float4*)verts, verts4, nvtx);
    }

    int vpb = (V + 255) / 256;               // 782 vertex-blocks per batch
    int bpx = (B + 7) / 8;                   // 4 batches per XCD
    int nblk = 8 * bpx * vpb;                // 25024
    if (use4)
        gather1<true><<<nblk, 256, 0, stream>>>(verts, verts4, cursor, ell, out, V, vpb, B);
    else
        gather1<false><<<nblk, 256, 0, stream>>>(verts, verts4, cursor, ell, out, V, vpb, B);
}

// Round 4
// 724.958 us; speedup vs baseline: 1.3968x; 1.0557x over previous
//
#include <hip/hip_runtime.h>

#define EPS 1e-12f
#define CAP 32   // ELL slots/vertex. deg ~ Poisson(6); P(deg>=32) ~ 1e-13/vertex -> no spill path
#define CAPU 8   // slots issued upfront / unrolled (P(deg>8) ~ 0.15, E[extra] ~ 0.35)

typedef unsigned long long ull;

// ---------------------------------------------------------------------------
// Pipeline: zero cursor -> prep (fill ELL + repack verts to float4, fused)
//           -> gather (batch pinned to XCD; ALL 8 ELL slots issued upfront)
//
// ELL entry at slot s of vertex v stores the other two indices (a,b) of one
// incident face corner, in cyclic order; contribution = (A-v) x (B-v) equals
// the reference's cross(v2-v1, v0-v1) for every corner (cyclic identity).
//
// Regime learned (r0-r3): fabric scatter traffic saturates ~3.7 TB/s and
// dur ~ FETCH_SIZE when thrashing; with one batch per XCD (3.2 MB verts4
// < 4 MiB L2) FETCH collapses but the loop became LATENCY-bound (539 us,
// VALUBusy 13%): NT ELL loads (~HBM latency) prefetched only 1 slot ahead
// + only 2 random loads in flight. Fix: front-load all CAPU ELL loads
// (unconditional issue -- in-bounds; values used only when s<deg) and the
// center/deg loads, then an unrolled compute phase with up to 16
// independent random L2-hit loads in flight.
// ---------------------------------------------------------------------------

__global__ void zero_ints(int* __restrict__ p, int n) {
    int i = blockIdx.x * blockDim.x + threadIdx.x;
    if (i < n) p[i] = 0;
}

// fused: fill ELL (t < F) + repack 4 vertices float3->float4 (t < nrep)
__global__ void prep_kernel(const int* __restrict__ faces, int* __restrict__ cursor,
                            int2* __restrict__ ell, int F, int V,
                            const float4* __restrict__ in4, float4* __restrict__ out4,
                            int nrep) {
    int t = blockIdx.x * blockDim.x + threadIdx.x;
    if (t < nrep) {
        float4 a = in4[3 * (size_t)t + 0];
        float4 b = in4[3 * (size_t)t + 1];
        float4 c = in4[3 * (size_t)t + 2];
        out4[4 * (size_t)t + 0] = make_float4(a.x, a.y, a.z, 0.f);
        out4[4 * (size_t)t + 1] = make_float4(a.w, b.x, b.y, 0.f);
        out4[4 * (size_t)t + 2] = make_float4(b.z, b.w, c.x, 0.f);
        out4[4 * (size_t)t + 3] = make_float4(c.y, c.z, c.w, 0.f);
    }
    if (t < F) {
        int i0 = faces[3 * t + 0];
        int i1 = faces[3 * t + 1];
        int i2 = faces[3 * t + 2];
        int vs[3] = {i0, i1, i2};
        int as[3] = {i1, i2, i0};
        int bs[3] = {i2, i0, i1};
#pragma unroll
        for (int c = 0; c < 3; c++) {
            int v = vs[c];
            int slot = atomicAdd(&cursor[v], 1);
            if (slot < CAP) ell[slot * V + v] = make_int2(as[c], bs[c]);
        }
    }
}

__global__ __launch_bounds__(256) void gather1(const float4* __restrict__ verts4,
                                               const int* __restrict__ deg,
                                               const int2* __restrict__ ell,
                                               float* __restrict__ out,
                                               int V, int vpb, int B) {
    int i = blockIdx.x;
    int xcd = i & 7;                 // round-robin dispatch -> XCD id
    int j = i >> 3;
    int lb = j / vpb;                // local batch index on this XCD
    int vblk = j - lb * vpb;
    int batch = lb * 8 + xcd;
    if (batch >= B) return;
    int v = vblk * 256 + threadIdx.x;
    if (v >= V) return;

    const float4* vb4 = verts4 + (size_t)batch * V;

    // front-load everything independent: deg, center, all CAPU ELL slots
    int d = min(deg[v], CAP);        // temporal: 800KB, L2-resident, gates all
    float4 c = vb4[v];
    const ull* ep = (const ull*)ell;
    ull e[CAPU];
#pragma unroll
    for (int s = 0; s < CAPU; s++)   // unconditional issue: in-bounds (s < CAP)
        e[s] = __builtin_nontemporal_load(ep + (size_t)s * V + v);

    float vx = c.x, vy = c.y, vz = c.z;
    float ax = 0.f, ay = 0.f, az = 0.f;
    int dc = min(d, CAPU);
#pragma unroll
    for (int s = 0; s < CAPU; s++) {
        if (s < dc) {
            int pa = (int)(unsigned int)(e[s] & 0xffffffffull);
            int pb = (int)(unsigned int)(e[s] >> 32);
            float4 A = vb4[pa];
            float4 Bq = vb4[pb];
            float aX = A.x - vx, aY = A.y - vy, aZ = A.z - vz;
            float bX = Bq.x - vx, bY = Bq.y - vy, bZ = Bq.z - vz;
            ax += aY * bZ - aZ * bY;
            ay += aZ * bX - aX * bZ;
            az += aX * bY - aY * bX;
        }
    }
    // rare tail: deg > CAPU (P ~ 0.15, avg 2-3 extra slots when taken)
    for (int s = CAPU; s < d; s++) {
        ull cur = __builtin_nontemporal_load(ep + (size_t)s * V + v);
        int pa = (int)(unsigned int)(cur & 0xffffffffull);
        int pb = (int)(unsigned int)(cur >> 32);
        float4 A = vb4[pa];
        float4 Bq = vb4[pb];
        float aX = A.x - vx, aY = A.y - vy, aZ = A.z - vz;
        float bX = Bq.x - vx, bY = Bq.y - vy, bZ = Bq.z - vz;
        ax += aY * bZ - aZ * bY;
        ay += aZ * bX - aX * bZ;
        az += aX * bY - aY * bX;
    }

    float sc = rsqrtf(fmaxf(ax * ax + ay * ay + az * az, EPS));
    size_t o = ((size_t)batch * V + v) * 3;
    __builtin_nontemporal_store(ax * sc, out + o + 0);
    __builtin_nontemporal_store(ay * sc, out + o + 1);
    __builtin_nontemporal_store(az * sc, out + o + 2);
}

extern "C" void kernel_launch(void* const* d_in, const int* in_sizes, int n_in,
                              void* d_out, int out_size, void* d_ws, size_t ws_size,
                              hipStream_t stream) {
    const float* verts = (const float*)d_in[0];
    const int* faces = (const int*)d_in[1];
    float* out = (float*)d_out;

    const int V = 200000;
    const int F = in_sizes[1] / 3;           // 400000
    const int B = in_sizes[0] / (3 * V);     // 32

    // workspace: verts4[B*V] | cursor[V] | ell[CAP*V]  (~154 MB, proven to fit r3)
    char* w = (char*)d_ws;
    float4* verts4 = (float4*)w; w += (size_t)B * V * sizeof(float4);
    int* cursor = (int*)w;       w += (size_t)V * sizeof(int);
    int2* ell = (int2*)w;

    zero_ints<<<(V + 255) / 256, 256, 0, stream>>>(cursor, V);

    int nrep = (B * V) / 4;                  // 1.6M repack threads (B*V % 4 == 0)
    int nprep = max(nrep, F);
    prep_kernel<<<(nprep + 255) / 256, 256, 0, stream>>>(
        faces, cursor, ell, F, V, (const float4*)verts, verts4, nrep);

    int vpb = (V + 255) / 256;               // 782 vertex-blocks per batch
    int bpx = (B + 7) / 8;                   // 4 batches per XCD
    int nblk = 8 * bpx * vpb;                // 25024
    gather1<<<nblk, 256, 0, stream>>>(verts4, cursor, ell, out, V, vpb, B);
}